// Round 11
// baseline (4475.799 us; speedup 1.0000x reference)
//
#include <hip/hip_runtime.h>
#include <math.h>

// Point-MAE Group — FPS(2048) + kNN(16) + gather/subtract.
// B=4, N=16384, G=2048, M=16.
// NUMERICS CONTRACT (verified absmax=0.0 in rounds 4-10 — do not change):
//  - FPS: d = ((dx*dx)+(dy*dy))+(dz*dz), all separate f32 ops, no FMA.
//  - kNN: d2 = (cc - 2*dot) + xx; ONLY dot is an FMA chain (numpy einsum).
//  - FPS argmax: first occurrence of max; top-16: stable ascending order.
//
// Round-11: r6/r9/r10 (three different memory structures) all land 3.8-4.3ms
// at VALU ~75% busy on the active CUs -> the serial loop is VALU-ISSUE-bound.
// This round cuts instructions/point ~2x:
//  - packed f32 (VOP3P v_pk_add_f32/v_pk_mul_f32, 2 pts/inst) for the
//    distance chain. Each packed op = two independent IEEE f32 ops ->
//    bit-identical per component. sub done as x + (-p) (exact identity).
//  - LDS pair-transposed XP/YP[8192] (128KB): all ds_read_b64 offsets are
//    immediates (j*4096 <= 61440), zero address VALU in the loop.
//    z+md in registers as float2 (sub-reg .x/.y access is free).
//  - inner loop tracks only min+max (no per-point cmp/cndmask); winning
//    local index recovered by descending equality scan (md[i]==bv,
//    overwrite => first occurrence of max — same index as sequential scan).
//  - tail: r6's proven form (u64-key butterfly; lane0 global-reads winner
//    coords under the barrier; single barrier; 8-key scan).

#pragma clang fp contract(off)

#define N_PTS 16384
#define N_GROUP 2048
#define GROUP_SIZE 16
#define FPS_THREADS 512
#define NPAIR 16                      // 32 points = 16 packed pairs per thread
#define FPS_WAVES (FPS_THREADS / 64)
#define KNN_THREADS 256
#define KNN_WAVES (KNN_THREADS / 64)

// a*b as a standalone instruction (kNN only — keep the exact passing form).
__device__ __forceinline__ float fmul_sep(float a, float b) {
  float r = a * b;
  asm volatile("" : "+v"(r));
  return r;
}

__device__ __forceinline__ unsigned long long shfl_xor_u64(unsigned long long v, int off) {
  const unsigned int lo = __shfl_xor((unsigned int)v, off);
  const unsigned int hi = __shfl_xor((unsigned int)(v >> 32), off);
  return ((unsigned long long)hi << 32) | lo;
}

__device__ __forceinline__ float2 pk_add(float2 a, float2 b) {
  float2 d;
  asm("v_pk_add_f32 %0, %1, %2" : "=v"(d) : "v"(a), "v"(b));
  return d;
}
__device__ __forceinline__ float2 pk_sq(float2 a) {
  float2 d;
  asm("v_pk_mul_f32 %0, %1, %1" : "=v"(d) : "v"(a));
  return d;
}

// ---------------------------------------------------------------------------
// FPS: one block per batch. XP/YP pair-transposed in LDS, Z/MD in registers.
// ---------------------------------------------------------------------------
__global__ __launch_bounds__(FPS_THREADS)
__attribute__((amdgpu_waves_per_eu(2, 2)))
void fps_kernel(const float* __restrict__ pcd, float* __restrict__ center) {
#pragma clang fp contract(off)
  const int b = blockIdx.x;
  const int t = threadIdx.x;
  const int lane = t & 63;
  const int wid = t >> 6;
  const float* xyz = pcd + (size_t)b * N_PTS * 3;

  // pair j of thread t = points (2j)*512+t (lo) and (2j+1)*512+t (hi)
  __shared__ float2 XP[NPAIR * FPS_THREADS];  // 64 KiB, [j*512+t]
  __shared__ float2 YP[NPAIR * FPS_THREADS];  // 64 KiB
  __shared__ unsigned long long skey[2][FPS_WAVES];
  __shared__ float sx[2][FPS_WAVES], sy[2][FPS_WAVES], sz[2][FPS_WAVES];

  float2 Z[NPAIR], MD[NPAIR];
#pragma unroll
  for (int j = 0; j < NPAIR; ++j) {
    const int i0 = (2 * j) * FPS_THREADS + t;
    const int i1 = i0 + FPS_THREADS;
    XP[j * FPS_THREADS + t] = make_float2(xyz[i0 * 3 + 0], xyz[i1 * 3 + 0]);
    YP[j * FPS_THREADS + t] = make_float2(xyz[i0 * 3 + 1], xyz[i1 * 3 + 1]);
    Z[j] = make_float2(xyz[i0 * 3 + 2], xyz[i1 * 3 + 2]);
    MD[j] = make_float2(1e10f, 1e10f);
  }
#pragma unroll
  for (int j = 0; j < NPAIR; ++j) asm("" : "+v"(Z[j]));  // forbid remat

  float px = xyz[0], py = xyz[1], pz = xyz[2];
  if (t == 0) {
    center[((size_t)b * N_GROUP) * 3 + 0] = px;
    center[((size_t)b * N_GROUP) * 3 + 1] = py;
    center[((size_t)b * N_GROUP) * 3 + 2] = pz;
  }
  __syncthreads();  // XP/YP ready

  for (int it = 1; it < N_GROUP; ++it) {
    const int p = it & 1;
    const float2 npx2 = make_float2(-px, -px);
    const float2 npy2 = make_float2(-py, -py);
    const float2 npz2 = make_float2(-pz, -pz);
    float bv = -1.0f;
#pragma unroll
    for (int j = 0; j < NPAIR; ++j) {
      const float2 dx = pk_add(XP[j * FPS_THREADS + t], npx2);  // x + (-px)
      const float2 dy = pk_add(YP[j * FPS_THREADS + t], npy2);
      const float2 dz = pk_add(Z[j], npz2);
      const float2 sxq = pk_sq(dx);
      const float2 syq = pk_sq(dy);
      const float2 szq = pk_sq(dz);
      const float2 s = pk_add(pk_add(sxq, syq), szq);  // ((dx²+dy²))+dz²
      MD[j].x = fminf(MD[j].x, s.x);
      MD[j].y = fminf(MD[j].y, s.y);
      bv = fmaxf(bv, MD[j].x);
      bv = fmaxf(bv, MD[j].y);
    }
    // first local index with md == bv (descending overwrite -> lowest wins)
    int ii = 0;
#pragma unroll
    for (int j = NPAIR - 1; j >= 0; --j) {
      if (MD[j].y == bv) ii = 2 * j + 1;
      if (MD[j].x == bv) ii = 2 * j;
    }
    const int bi = ii * FPS_THREADS + t;
    // bv >= 0 (squared distance), so IEEE bit order == value order.
    unsigned long long key =
        ((unsigned long long)__float_as_uint(bv) << 32) |
        (unsigned int)(N_PTS - 1 - bi);  // higher low-word = lower index

    // wave butterfly: max key (value, then lowest index)
#pragma unroll
    for (int off = 32; off > 0; off >>= 1) {
      const unsigned long long ok = shfl_xor_u64(key, off);
      if (ok > key) key = ok;
    }
    if (lane == 0) {
      // wave-winner coords: bit-copies straight from memory, hidden by barrier
      const int kidx = N_PTS - 1 - (int)(unsigned int)(key & 0xffffffffu);
      skey[p][wid] = key;
      sx[p][wid] = xyz[kidx * 3 + 0];
      sy[p][wid] = xyz[kidx * 3 + 1];
      sz[p][wid] = xyz[kidx * 3 + 2];
    }
    __syncthreads();
    // cross-wave: sequential scan of FPS_WAVES keys (broadcast LDS reads)
    unsigned long long bk = skey[p][0];
    int bj = 0;
#pragma unroll
    for (int j = 1; j < FPS_WAVES; ++j) {
      const unsigned long long kj = skey[p][j];
      if (kj > bk) { bk = kj; bj = j; }
    }
    px = sx[p][bj]; py = sy[p][bj]; pz = sz[p][bj];
    if (t == 0) {
      center[((size_t)b * N_GROUP + it) * 3 + 0] = px;
      center[((size_t)b * N_GROUP + it) * 3 + 1] = py;
      center[((size_t)b * N_GROUP + it) * 3 + 2] = pz;
    }
    // single barrier/iter: double-buffered slots fence reuse at it+2.
  }
}

// ---------------------------------------------------------------------------
// kNN: one wave per center; lanes 0..15 hold the sorted top-16.
// d2 = (cc - 2*dot) + xx; cc/xx separate ops; dot = FMA chain (einsum).
// (unchanged from the bit-exact round-4 version)
// ---------------------------------------------------------------------------
__global__ __launch_bounds__(KNN_THREADS) void knn_kernel(
    const float* __restrict__ pcd, const float* __restrict__ center,
    float* __restrict__ nbr) {
#pragma clang fp contract(off)
  const int lane = threadIdx.x & 63;
  const int gw = blockIdx.x * KNN_WAVES + (threadIdx.x >> 6);  // center id
  const int b = gw >> 11;                                      // G = 2048
  const float* xyz = pcd + (size_t)b * N_PTS * 3;

  const float c0 = center[(size_t)gw * 3 + 0];
  const float c1 = center[(size_t)gw * 3 + 1];
  const float c2 = center[(size_t)gw * 3 + 2];
  const float cc = (fmul_sep(c0, c0) + fmul_sep(c1, c1)) + fmul_sep(c2, c2);

  float lval = INFINITY;  // lanes 0..15: sorted list values (ascending)
  int lidx = 0;
  float worst = INFINITY; // 16th-smallest so far, wave-uniform

  for (int ch = 0; ch < N_PTS / 64; ++ch) {
    const int n = ch * 64 + lane;
    const float xp = xyz[n * 3 + 0];
    const float yp = xyz[n * 3 + 1];
    const float zp = xyz[n * 3 + 2];
    const float xx = (fmul_sep(xp, xp) + fmul_sep(yp, yp)) + fmul_sep(zp, zp);
    // numpy einsum: acc=0; acc=fma(c0,x,acc); acc=fma(c1,y,acc); acc=fma(c2,z,acc)
    const float dot = fmaf(c2, zp, fmaf(c1, yp, c0 * xp));
    const float d2 = (cc - fmul_sep(2.0f, dot)) + xx;

    unsigned long long m = __ballot(d2 < worst);
    while (m) {
      const int srcl = __ffsll((unsigned long long)m) - 1;  // ascending index
      m &= (m - 1);
      const float nv = __shfl(d2, srcl);
      if (nv < worst) {  // wave-uniform decision
        const int ni = ch * 64 + srcl;
        const int rank = __popcll(__ballot(lane < GROUP_SIZE && lval <= nv));
        const float shv = __shfl_up(lval, 1);
        const int   shi = __shfl_up(lidx, 1);
        if (lane < GROUP_SIZE) {
          if (lane == rank)      { lval = nv;  lidx = ni;  }
          else if (lane > rank)  { lval = shv; lidx = shi; }
        }
        worst = __shfl(lval, 15);
      }
    }
  }

  if (lane < GROUP_SIZE) {
    const float ox = xyz[lidx * 3 + 0] - c0;
    const float oy = xyz[lidx * 3 + 1] - c1;
    const float oz = xyz[lidx * 3 + 2] - c2;
    const size_t o = ((size_t)gw * GROUP_SIZE + lane) * 3;
    nbr[o + 0] = ox; nbr[o + 1] = oy; nbr[o + 2] = oz;
  }
}

extern "C" void kernel_launch(void* const* d_in, const int* in_sizes, int n_in,
                              void* d_out, int out_size, void* d_ws, size_t ws_size,
                              hipStream_t stream) {
  const float* pcd = (const float*)d_in[0];
  const int B = in_sizes[0] / (N_PTS * 3);  // = 4

  float* out = (float*)d_out;
  float* nbr = out;                                            // B*G*M*3
  float* center = out + (size_t)B * N_GROUP * GROUP_SIZE * 3;  // B*G*3

  fps_kernel<<<B, FPS_THREADS, 0, stream>>>(pcd, center);
  knn_kernel<<<(B * N_GROUP) / KNN_WAVES, KNN_THREADS, 0, stream>>>(pcd, center, nbr);
}